// Round 7
// baseline (347.749 us; speedup 1.0000x reference)
//
#include <hip/hip_runtime.h>

#define UN      100000
#define IN_     50000
#define DN      64
#define ERATE   1000000
#define ETRUST  500000
#define EPRED   200000
#define LAMDA   0.5f
#define LAMDA_T 0.25f

// Fixed-stride CSR buckets. Degrees ~ Poisson(10)/Poisson(5);
// P(any user exceeds 48 / 32) ~ 1e-13 / 1e-11. Guarded anyway.
#define STRIDE_R 48
#define STRIDE_T 32

// d_ws layout (byte offsets):
//   0           h       [UN*DN]        f32    25,600,000
//   25,600,000  csr_r   [UN*STRIDE_R]  i32    19,200,000
//   44,800,000  csr_t   [UN*STRIDE_T]  i32    12,800,000
//   --- zeroed region start ---
//   57,600,000  cur_r   [UN]  i32    400,000
//   58,000,000  cur_t   [UN]  i32    400,000
//   58,400,000  dri     [IN_] i32    200,000
//   58,600,000  dto     [UN]  i32    400,000
//   59,000,000  acc     [2]   f64         16
//   --- zeroed region end (350,004 words) ---
#define OFF_CSR_R (25600000 / 4)
#define OFF_CSR_T (44800000 / 4)
#define OFF_CUR_R (57600000 / 4)
#define OFF_CUR_T (58000000 / 4)
#define OFF_DRI   (58400000 / 4)
#define OFF_DTO   (58600000 / 4)
#define OFF_ACC_B 59000000
#define ZERO_N    350004

// role block counts
#define NB_FILLR 768
#define NB_FILLT 384
#define NB_LINK  1024
#define NB_HISTR 384
#define NB_HISTT 192
#define NB_GATH  25000   // ceil(UN/4)
#define NB_SCOR  25000   // 2*EPRED*16/256
#define NB_REG   512

__device__ __forceinline__ float degfac_i(int c) {
    return c > 0 ? rsqrtf((float)c) : 0.0f;
}

__global__ void k_zero(int* __restrict__ p, int n) {
    int i = blockIdx.x * blockDim.x + threadIdx.x;
    if (i < n) p[i] = 0;
}

// Batched bucket-fill: 4 independent return-atomics in flight, then 4 stores.
__device__ __forceinline__ void fill_batched(const int* __restrict__ key,
                                             const int* __restrict__ val, int n,
                                             int* __restrict__ cur, int* __restrict__ csr,
                                             int stride_c, int tid0, int gs) {
    int i = tid0;
    for (; i + 3 * gs < n; i += 4 * gs) {
        int k0 = key[i];
        int k1 = key[i + gs];
        int k2 = key[i + 2 * gs];
        int k3 = key[i + 3 * gs];
        int v0 = val[i];
        int v1 = val[i + gs];
        int v2 = val[i + 2 * gs];
        int v3 = val[i + 3 * gs];
        int p0 = atomicAdd(&cur[k0], 1);
        int p1 = atomicAdd(&cur[k1], 1);
        int p2 = atomicAdd(&cur[k2], 1);
        int p3 = atomicAdd(&cur[k3], 1);
        if (p0 < stride_c) csr[k0 * stride_c + p0] = v0;
        if (p1 < stride_c) csr[k1 * stride_c + p1] = v1;
        if (p2 < stride_c) csr[k2 * stride_c + p2] = v2;
        if (p3 < stride_c) csr[k3 * stride_c + p3] = v3;
    }
    for (; i < n; i += gs) {
        int k = key[i];
        int p = atomicAdd(&cur[k], 1);
        if (p < stride_c) csr[k * stride_c + p] = val[i];
    }
}

// A: fill_r | fill_t | link-loss
__global__ __launch_bounds__(256) void k_fillA(
        const int* __restrict__ rate_src, const int* __restrict__ rate_dst,
        const int* __restrict__ trust_src, const int* __restrict__ trust_dst,
        const float* __restrict__ yw_user, const float* __restrict__ pq_user,
        int* __restrict__ cur_r, int* __restrict__ csr_r,
        int* __restrict__ cur_t, int* __restrict__ csr_t,
        double* __restrict__ acc) {
    int b = blockIdx.x;
    if (b < NB_FILLR) {
        fill_batched(rate_src, rate_dst, ERATE, cur_r, csr_r, STRIDE_R,
                     b * 256 + threadIdx.x, NB_FILLR * 256);
    } else if (b < NB_FILLR + NB_FILLT) {
        fill_batched(trust_dst, trust_src, ETRUST, cur_t, csr_t, STRIDE_T,
                     (b - NB_FILLR) * 256 + threadIdx.x, NB_FILLT * 256);
    } else {
        int rb = b - NB_FILLR - NB_FILLT;
        int stride = NB_LINK * 256;
        float local = 0.0f;
        const int TOT = ETRUST * 16;
        for (int tid = rb * 256 + threadIdx.x; tid < TOT; tid += stride) {
            int e = tid >> 4;
            int c = (tid & 15) << 2;
            int s = trust_src[e], d = trust_dst[e];
            float4 a = *reinterpret_cast<const float4*>(yw_user + ((long)s << 6) + c);
            float4 bb = *reinterpret_cast<const float4*>(pq_user + ((long)d << 6) + c);
            float dot = a.x * bb.x + a.y * bb.y + a.z * bb.z + a.w * bb.w;
            #pragma unroll
            for (int off = 1; off < 16; off <<= 1) dot += __shfl_xor(dot, off);
            if ((tid & 15) == 0) { float dm = dot - 1.0f; local += dm * dm; }
        }
        #pragma unroll
        for (int off = 32; off > 0; off >>= 1) local += __shfl_xor(local, off);
        __shared__ float red[4];
        if ((threadIdx.x & 63) == 0) red[threadIdx.x >> 6] = local;
        __syncthreads();
        if (threadIdx.x == 0) unsafeAtomicAdd(acc, (double)(red[0] + red[1] + red[2] + red[3]));
    }
}

__device__ __forceinline__ void hist_batched(const int* __restrict__ key, int n,
                                             int* __restrict__ cnt, int tid0, int gs) {
    int i = tid0;
    for (; i + 3 * gs < n; i += 4 * gs) {
        int k0 = key[i];
        int k1 = key[i + gs];
        int k2 = key[i + 2 * gs];
        int k3 = key[i + 3 * gs];
        atomicAdd(&cnt[k0], 1);
        atomicAdd(&cnt[k1], 1);
        atomicAdd(&cnt[k2], 1);
        atomicAdd(&cnt[k3], 1);
    }
    for (; i < n; i += gs) atomicAdd(&cnt[key[i]], 1);
}

// B: hist_dri | hist_dto | gather (hists at low blockIdx -> dispatch first)
__global__ __launch_bounds__(256) void k_gathB(
        const int* __restrict__ rate_dst, const int* __restrict__ trust_src,
        const float* __restrict__ pq_user, const float* __restrict__ yw_item,
        const float* __restrict__ yw_user,
        const int* __restrict__ cur_r, const int* __restrict__ csr_r,
        const int* __restrict__ cur_t, const int* __restrict__ csr_t,
        int* __restrict__ dri, int* __restrict__ dto,
        float* __restrict__ h) {
    int b = blockIdx.x;
    if (b < NB_HISTR) {
        hist_batched(rate_dst, ERATE, dri, b * 256 + threadIdx.x, NB_HISTR * 256);
        return;
    }
    if (b < NB_HISTR + NB_HISTT) {
        hist_batched(trust_src, ETRUST, dto, (b - NB_HISTR) * 256 + threadIdx.x, NB_HISTT * 256);
        return;
    }
    int w = ((b - NB_HISTR - NB_HISTT) << 2) + (threadIdx.x >> 6);
    if (w >= UN) return;
    int lane = threadIdx.x & 63;
    int grp = lane >> 4;          // edge slot 0..3
    int c4 = (lane & 15) << 2;    // column offset

    float sx = 0.f, sy = 0.f, sz = 0.f, sw = 0.f;
    float tx = 0.f, ty = 0.f, tz = 0.f, tw = 0.f;
    int cr = cur_r[w]; if (cr > STRIDE_R) cr = STRIDE_R;
    int ct = cur_t[w]; if (ct > STRIDE_T) ct = STRIDE_T;

    {
        int my = (lane < cr) ? csr_r[w * STRIDE_R + lane] : 0;
        for (int j = 0; j < cr; j += 4) {
            int e = j + grp;                 // <= 50 < 64
            int r = __shfl(my, e);           // full-wave shfl (defined sources)
            if (e < cr) {
                const float4 v = *reinterpret_cast<const float4*>(yw_item + ((long)r << 6) + c4);
                sx += v.x; sy += v.y; sz += v.z; sw += v.w;
            }
        }
    }
    {
        int my = (lane < ct) ? csr_t[w * STRIDE_T + lane] : 0;
        for (int j = 0; j < ct; j += 4) {
            int e = j + grp;
            int r = __shfl(my, e);
            if (e < ct) {
                const float4 v = *reinterpret_cast<const float4*>(yw_user + ((long)r << 6) + c4);
                tx += v.x; ty += v.y; tz += v.z; tw += v.w;
            }
        }
    }
    float fr = degfac_i(cur_r[w]), ft = degfac_i(cur_t[w]);
    float rx = fr * sx + ft * tx;
    float ry = fr * sy + ft * ty;
    float rz = fr * sz + ft * tz;
    float rw = fr * sw + ft * tw;
    rx += __shfl_xor(rx, 16); rx += __shfl_xor(rx, 32);
    ry += __shfl_xor(ry, 16); ry += __shfl_xor(ry, 32);
    rz += __shfl_xor(rz, 16); rz += __shfl_xor(rz, 32);
    rw += __shfl_xor(rw, 16); rw += __shfl_xor(rw, 32);
    if (grp == 0) {
        const float4 p = *reinterpret_cast<const float4*>(pq_user + ((long)w << 6) + c4);
        float4 o4 = make_float4(p.x + rx, p.y + ry, p.z + rz, p.w + rw);
        *reinterpret_cast<float4*>(h + ((long)w << 6) + c4) = o4;
    }
}

// C: scores | reg-loss
__global__ __launch_bounds__(256) void k_scorC(
        const float* __restrict__ h, const float* __restrict__ pq_item,
        const float* __restrict__ pq_user, const float* __restrict__ yw_user,
        const float* __restrict__ yw_item,
        const float* __restrict__ b_user, const float* __restrict__ b_item,
        const float* __restrict__ gb,
        const int* __restrict__ ps, const int* __restrict__ pd,
        const int* __restrict__ ns, const int* __restrict__ nd,
        const int* __restrict__ cur_r, const int* __restrict__ cur_t,
        const int* __restrict__ dto, const int* __restrict__ dri,
        double* __restrict__ acc, float* __restrict__ out) {
    int b = blockIdx.x;
    if (b < NB_SCOR) {
        int tid = b * 256 + threadIdx.x;
        int e = tid >> 4;
        int c = (tid & 15) << 2;
        bool pos = e < EPRED;
        int idx = pos ? e : e - EPRED;
        int s = (pos ? ps : ns)[idx];
        int d = (pos ? pd : nd)[idx];
        float4 a = *reinterpret_cast<const float4*>(h + ((long)s << 6) + c);
        float4 bb = *reinterpret_cast<const float4*>(pq_item + ((long)d << 6) + c);
        float dot = a.x * bb.x + a.y * bb.y + a.z * bb.z + a.w * bb.w;
        #pragma unroll
        for (int off = 1; off < 16; off <<= 1) dot += __shfl_xor(dot, off);
        if ((tid & 15) == 0) out[e] = dot + b_user[s] + b_item[d] + gb[0];
    } else {
        int rb = b - NB_SCOR;
        int stride = NB_REG * 256;
        float local = 0.0f;
        const int TOT = (UN + IN_) * 16;
        for (int tid = rb * 256 + threadIdx.x; tid < TOT; tid += stride) {
            int r = tid >> 4;
            int c = (tid & 15) << 2;
            if (r < UN) {
                float4 p = *reinterpret_cast<const float4*>(pq_user + ((long)r << 6) + c);
                float4 y = *reinterpret_cast<const float4*>(yw_user + ((long)r << 6) + c);
                float sp = p.x * p.x + p.y * p.y + p.z * p.z + p.w * p.w;
                float sy = y.x * y.x + y.y * y.y + y.z * y.z + y.w * y.w;
                #pragma unroll
                for (int off = 1; off < 16; off <<= 1) {
                    sp += __shfl_xor(sp, off);
                    sy += __shfl_xor(sy, off);
                }
                if ((tid & 15) == 0) {
                    float Iu  = degfac_i(cur_r[r]);
                    float Tu  = degfac_i(cur_t[r]);
                    float Tvp = degfac_i(dto[r]);
                    float bb  = b_user[r];
                    local += ((LAMDA * Iu) * (bb * bb)
                            + (LAMDA * Iu + LAMDA_T * Tu) * sp
                            + (LAMDA_T * Tvp) * sy) * (1.0f / UN);
                }
            } else {
                int it = r - UN;
                float4 p = *reinterpret_cast<const float4*>(pq_item + ((long)it << 6) + c);
                float4 y = *reinterpret_cast<const float4*>(yw_item + ((long)it << 6) + c);
                float sp = p.x * p.x + p.y * p.y + p.z * p.z + p.w * p.w;
                float sy = y.x * y.x + y.y * y.y + y.z * y.z + y.w * y.w;
                #pragma unroll
                for (int off = 1; off < 16; off <<= 1) {
                    sp += __shfl_xor(sp, off);
                    sy += __shfl_xor(sy, off);
                }
                if ((tid & 15) == 0) {
                    float Uj = degfac_i(dri[it]);
                    float bb = b_item[it];
                    local += (LAMDA * Uj) * (bb * bb + sp + sy) * (1.0f / IN_);
                }
            }
        }
        #pragma unroll
        for (int off = 32; off > 0; off >>= 1) local += __shfl_xor(local, off);
        __shared__ float red[4];
        if ((threadIdx.x & 63) == 0) red[threadIdx.x >> 6] = local;
        __syncthreads();
        if (threadIdx.x == 0) unsafeAtomicAdd(acc + 1, (double)(red[0] + red[1] + red[2] + red[3]));
    }
}

__global__ void k_final(const double* __restrict__ acc, float* __restrict__ out) {
    if (threadIdx.x == 0 && blockIdx.x == 0) {
        out[2 * EPRED]     = (float)acc[1];
        out[2 * EPRED + 1] = (float)(LAMDA_T * acc[0] / (double)ETRUST);
    }
}

extern "C" void kernel_launch(void* const* d_in, const int* in_sizes, int n_in,
                              void* d_out, int out_size, void* d_ws, size_t ws_size,
                              hipStream_t stream) {
    const float* pq_user = (const float*)d_in[0];
    const float* pq_item = (const float*)d_in[1];
    const float* yw_user = (const float*)d_in[2];
    const float* yw_item = (const float*)d_in[3];
    const float* b_user  = (const float*)d_in[4];
    const float* b_item  = (const float*)d_in[5];
    const float* gb      = (const float*)d_in[6];
    const int* rate_src  = (const int*)d_in[7];
    const int* rate_dst  = (const int*)d_in[8];
    const int* trust_src = (const int*)d_in[9];
    const int* trust_dst = (const int*)d_in[10];
    const int* pos_src   = (const int*)d_in[11];
    const int* pos_dst   = (const int*)d_in[12];
    const int* neg_src   = (const int*)d_in[13];
    const int* neg_dst   = (const int*)d_in[14];

    float* ws   = (float*)d_ws;
    int*   wsi  = (int*)d_ws;
    float* h     = ws;
    int*   csr_r = wsi + OFF_CSR_R;
    int*   csr_t = wsi + OFF_CSR_T;
    int*   cur_r = wsi + OFF_CUR_R;
    int*   cur_t = wsi + OFF_CUR_T;
    int*   dri   = wsi + OFF_DRI;
    int*   dto   = wsi + OFF_DTO;
    double* acc  = (double*)((char*)d_ws + OFF_ACC_B);
    float* out   = (float*)d_out;

    // 1. zero cursors/hists/acc (contiguous)
    k_zero<<<(ZERO_N + 255) / 256, 256, 0, stream>>>(wsi + OFF_CUR_R, ZERO_N);
    // 2. A: batched bucket fills + link loss
    k_fillA<<<NB_FILLR + NB_FILLT + NB_LINK, 256, 0, stream>>>(
        rate_src, rate_dst, trust_src, trust_dst, yw_user, pq_user,
        cur_r, csr_r, cur_t, csr_t, acc);
    // 3. B: batched degree histograms + gather h
    k_gathB<<<NB_HISTR + NB_HISTT + NB_GATH, 256, 0, stream>>>(
        rate_dst, trust_src, pq_user, yw_item, yw_user,
        cur_r, csr_r, cur_t, csr_t, dri, dto, h);
    // 4. C: scores + reg loss
    k_scorC<<<NB_SCOR + NB_REG, 256, 0, stream>>>(
        h, pq_item, pq_user, yw_user, yw_item, b_user, b_item, gb,
        pos_src, pos_dst, neg_src, neg_dst,
        cur_r, cur_t, dto, dri, acc, out);
    // 5. finalize scalars
    k_final<<<1, 64, 0, stream>>>(acc, out);
}

// Round 8
// 333.451 us; speedup vs baseline: 1.0429x; 1.0429x over previous
//
#include <hip/hip_runtime.h>

#define UN      100000
#define IN_     50000
#define DN      64
#define ERATE   1000000
#define ETRUST  500000
#define EPRED   200000
#define LAMDA   0.5f
#define LAMDA_T 0.25f

// Fixed-stride CSR buckets. Degrees ~ Poisson(10)/Poisson(5);
// P(any user exceeds 48 / 32) ~ 1e-13 / 1e-11. Guarded anyway.
#define STRIDE_R 48
#define STRIDE_T 32

// d_ws layout (byte offsets):
//   0           h       [UN*DN]        f32    25,600,000
//   25,600,000  csr_r   [UN*STRIDE_R]  i32    19,200,000
//   44,800,000  csr_t   [UN*STRIDE_T]  i32    12,800,000
//   --- zeroed region start ---
//   57,600,000  cur_r   [UN]  i32    400,000
//   58,000,000  cur_t   [UN]  i32    400,000
//   58,400,000  dri     [IN_] i32    200,000
//   58,600,000  dto     [UN]  i32    400,000
//   59,000,000  acc     [2]   f64         16
//   --- zeroed region end (350,004 words) ---
#define OFF_CSR_R (25600000 / 4)
#define OFF_CSR_T (44800000 / 4)
#define OFF_CUR_R (57600000 / 4)
#define OFF_CUR_T (58000000 / 4)
#define OFF_DRI   (58400000 / 4)
#define OFF_DTO   (58600000 / 4)
#define OFF_ACC_B 59000000
#define ZERO_N    350004

// role block counts
#define NB_FILLR 768
#define NB_FILLT 384
#define NB_LINK  1024
#define NB_HISTR 384
#define NB_HISTT 192
#define NB_GATH  25000   // ceil(UN/4)
#define NB_SCOR  12500   // 2*EPRED / 32 edges-per-block
#define NB_REG   512

__device__ __forceinline__ float degfac_i(int c) {
    return c > 0 ? rsqrtf((float)c) : 0.0f;
}

__global__ void k_zero(int* __restrict__ p, int n) {
    int i = blockIdx.x * blockDim.x + threadIdx.x;
    if (i < n) p[i] = 0;
}

// Batched bucket-fill: 4 independent return-atomics in flight, then 4 stores.
__device__ __forceinline__ void fill_batched(const int* __restrict__ key,
                                             const int* __restrict__ val, int n,
                                             int* __restrict__ cur, int* __restrict__ csr,
                                             int stride_c, int tid0, int gs) {
    int i = tid0;
    for (; i + 3 * gs < n; i += 4 * gs) {
        int k0 = key[i];
        int k1 = key[i + gs];
        int k2 = key[i + 2 * gs];
        int k3 = key[i + 3 * gs];
        int v0 = val[i];
        int v1 = val[i + gs];
        int v2 = val[i + 2 * gs];
        int v3 = val[i + 3 * gs];
        int p0 = atomicAdd(&cur[k0], 1);
        int p1 = atomicAdd(&cur[k1], 1);
        int p2 = atomicAdd(&cur[k2], 1);
        int p3 = atomicAdd(&cur[k3], 1);
        if (p0 < stride_c) csr[k0 * stride_c + p0] = v0;
        if (p1 < stride_c) csr[k1 * stride_c + p1] = v1;
        if (p2 < stride_c) csr[k2 * stride_c + p2] = v2;
        if (p3 < stride_c) csr[k3 * stride_c + p3] = v3;
    }
    for (; i < n; i += gs) {
        int k = key[i];
        int p = atomicAdd(&cur[k], 1);
        if (p < stride_c) csr[k * stride_c + p] = val[i];
    }
}

// A: fill_r | fill_t | link-loss
__global__ __launch_bounds__(256) void k_fillA(
        const int* __restrict__ rate_src, const int* __restrict__ rate_dst,
        const int* __restrict__ trust_src, const int* __restrict__ trust_dst,
        const float* __restrict__ yw_user, const float* __restrict__ pq_user,
        int* __restrict__ cur_r, int* __restrict__ csr_r,
        int* __restrict__ cur_t, int* __restrict__ csr_t,
        double* __restrict__ acc) {
    int b = blockIdx.x;
    if (b < NB_FILLR) {
        fill_batched(rate_src, rate_dst, ERATE, cur_r, csr_r, STRIDE_R,
                     b * 256 + threadIdx.x, NB_FILLR * 256);
    } else if (b < NB_FILLR + NB_FILLT) {
        fill_batched(trust_dst, trust_src, ETRUST, cur_t, csr_t, STRIDE_T,
                     (b - NB_FILLR) * 256 + threadIdx.x, NB_FILLT * 256);
    } else {
        int rb = b - NB_FILLR - NB_FILLT;
        int stride = NB_LINK * 256;
        float local = 0.0f;
        const int TOT = ETRUST * 16;
        for (int tid = rb * 256 + threadIdx.x; tid < TOT; tid += stride) {
            int e = tid >> 4;
            int c = (tid & 15) << 2;
            int s = trust_src[e], d = trust_dst[e];
            float4 a = *reinterpret_cast<const float4*>(yw_user + ((long)s << 6) + c);
            float4 bb = *reinterpret_cast<const float4*>(pq_user + ((long)d << 6) + c);
            float dot = a.x * bb.x + a.y * bb.y + a.z * bb.z + a.w * bb.w;
            #pragma unroll
            for (int off = 1; off < 16; off <<= 1) dot += __shfl_xor(dot, off);
            if ((tid & 15) == 0) { float dm = dot - 1.0f; local += dm * dm; }
        }
        #pragma unroll
        for (int off = 32; off > 0; off >>= 1) local += __shfl_xor(local, off);
        __shared__ float red[4];
        if ((threadIdx.x & 63) == 0) red[threadIdx.x >> 6] = local;
        __syncthreads();
        if (threadIdx.x == 0) unsafeAtomicAdd(acc, (double)(red[0] + red[1] + red[2] + red[3]));
    }
}

__device__ __forceinline__ void hist_batched(const int* __restrict__ key, int n,
                                             int* __restrict__ cnt, int tid0, int gs) {
    int i = tid0;
    for (; i + 3 * gs < n; i += 4 * gs) {
        int k0 = key[i];
        int k1 = key[i + gs];
        int k2 = key[i + 2 * gs];
        int k3 = key[i + 3 * gs];
        atomicAdd(&cnt[k0], 1);
        atomicAdd(&cnt[k1], 1);
        atomicAdd(&cnt[k2], 1);
        atomicAdd(&cnt[k3], 1);
    }
    for (; i < n; i += gs) atomicAdd(&cnt[key[i]], 1);
}

// B: hist_dri | hist_dto | gather (hists at low blockIdx -> dispatch first).
// Gather: 4 lane-groups x 2-edge unroll = 8 independent row-loads in flight.
__global__ __launch_bounds__(256) void k_gathB(
        const int* __restrict__ rate_dst, const int* __restrict__ trust_src,
        const float* __restrict__ pq_user, const float* __restrict__ yw_item,
        const float* __restrict__ yw_user,
        const int* __restrict__ cur_r, const int* __restrict__ csr_r,
        const int* __restrict__ cur_t, const int* __restrict__ csr_t,
        int* __restrict__ dri, int* __restrict__ dto,
        float* __restrict__ h) {
    int b = blockIdx.x;
    if (b < NB_HISTR) {
        hist_batched(rate_dst, ERATE, dri, b * 256 + threadIdx.x, NB_HISTR * 256);
        return;
    }
    if (b < NB_HISTR + NB_HISTT) {
        hist_batched(trust_src, ETRUST, dto, (b - NB_HISTR) * 256 + threadIdx.x, NB_HISTT * 256);
        return;
    }
    int w = ((b - NB_HISTR - NB_HISTT) << 2) + (threadIdx.x >> 6);
    if (w >= UN) return;
    int lane = threadIdx.x & 63;
    int grp = lane >> 4;          // edge slot 0..3
    int c4 = (lane & 15) << 2;    // column offset

    float ax = 0.f, ay = 0.f, az = 0.f, aw = 0.f;   // accumulator set 0
    float bx = 0.f, by = 0.f, bz = 0.f, bw = 0.f;   // accumulator set 1
    float tx = 0.f, ty = 0.f, tz = 0.f, tw = 0.f;   // trust set 0
    float ux = 0.f, uy = 0.f, uz = 0.f, uw = 0.f;   // trust set 1
    int cr = cur_r[w]; if (cr > STRIDE_R) cr = STRIDE_R;
    int ct = cur_t[w]; if (ct > STRIDE_T) ct = STRIDE_T;

    // rate side: cr <= 48; shfl unconditional (full exec), loads guarded.
    {
        int my = (lane < cr) ? csr_r[w * STRIDE_R + lane] : 0;
        for (int j = 0; j < cr; j += 8) {
            int e0 = j + grp;          // <= 47+3 < 64
            int e1 = j + 4 + grp;
            int r0 = __shfl(my, e0);
            int r1 = __shfl(my, e1);
            if (e0 < cr) {
                const float4 v = *reinterpret_cast<const float4*>(yw_item + ((long)r0 << 6) + c4);
                ax += v.x; ay += v.y; az += v.z; aw += v.w;
            }
            if (e1 < cr) {
                const float4 v = *reinterpret_cast<const float4*>(yw_item + ((long)r1 << 6) + c4);
                bx += v.x; by += v.y; bz += v.z; bw += v.w;
            }
        }
    }
    // trust side: ct <= 32
    {
        int my = (lane < ct) ? csr_t[w * STRIDE_T + lane] : 0;
        for (int j = 0; j < ct; j += 8) {
            int e0 = j + grp;
            int e1 = j + 4 + grp;
            int r0 = __shfl(my, e0);
            int r1 = __shfl(my, e1);
            if (e0 < ct) {
                const float4 v = *reinterpret_cast<const float4*>(yw_user + ((long)r0 << 6) + c4);
                tx += v.x; ty += v.y; tz += v.z; tw += v.w;
            }
            if (e1 < ct) {
                const float4 v = *reinterpret_cast<const float4*>(yw_user + ((long)r1 << 6) + c4);
                ux += v.x; uy += v.y; uz += v.z; uw += v.w;
            }
        }
    }
    float fr = degfac_i(cur_r[w]), ft = degfac_i(cur_t[w]);
    float rx = fr * (ax + bx) + ft * (tx + ux);
    float ry = fr * (ay + by) + ft * (ty + uy);
    float rz = fr * (az + bz) + ft * (tz + uz);
    float rw = fr * (aw + bw) + ft * (tw + uw);
    rx += __shfl_xor(rx, 16); rx += __shfl_xor(rx, 32);
    ry += __shfl_xor(ry, 16); ry += __shfl_xor(ry, 32);
    rz += __shfl_xor(rz, 16); rz += __shfl_xor(rz, 32);
    rw += __shfl_xor(rw, 16); rw += __shfl_xor(rw, 32);
    if (grp == 0) {
        const float4 p = *reinterpret_cast<const float4*>(pq_user + ((long)w << 6) + c4);
        float4 o4 = make_float4(p.x + rx, p.y + ry, p.z + rz, p.w + rw);
        *reinterpret_cast<float4*>(h + ((long)w << 6) + c4) = o4;
    }
}

// C: scores | reg-loss. Scores: 2 edges per 16-lane group (4 loads in flight),
// lane0 writes a coalesced float2 pair.
__global__ __launch_bounds__(256) void k_scorC(
        const float* __restrict__ h, const float* __restrict__ pq_item,
        const float* __restrict__ pq_user, const float* __restrict__ yw_user,
        const float* __restrict__ yw_item,
        const float* __restrict__ b_user, const float* __restrict__ b_item,
        const float* __restrict__ gb,
        const int* __restrict__ ps, const int* __restrict__ pd,
        const int* __restrict__ ns, const int* __restrict__ nd,
        const int* __restrict__ cur_r, const int* __restrict__ cur_t,
        const int* __restrict__ dto, const int* __restrict__ dri,
        double* __restrict__ acc, float* __restrict__ out) {
    int b = blockIdx.x;
    if (b < NB_SCOR) {
        int g = (b * 256 + threadIdx.x) >> 4;   // group id
        int c = (threadIdx.x & 15) << 2;
        int e0 = g * 2, e1 = g * 2 + 1;         // both < 2*EPRED
        bool p0 = e0 < EPRED, p1 = e1 < EPRED;
        int i0 = p0 ? e0 : e0 - EPRED;
        int i1 = p1 ? e1 : e1 - EPRED;
        int s0 = (p0 ? ps : ns)[i0];
        int d0 = (p0 ? pd : nd)[i0];
        int s1 = (p1 ? ps : ns)[i1];
        int d1 = (p1 ? pd : nd)[i1];
        float4 ha = *reinterpret_cast<const float4*>(h + ((long)s0 << 6) + c);
        float4 ia = *reinterpret_cast<const float4*>(pq_item + ((long)d0 << 6) + c);
        float4 hb = *reinterpret_cast<const float4*>(h + ((long)s1 << 6) + c);
        float4 ib = *reinterpret_cast<const float4*>(pq_item + ((long)d1 << 6) + c);
        float dot0 = ha.x * ia.x + ha.y * ia.y + ha.z * ia.z + ha.w * ia.w;
        float dot1 = hb.x * ib.x + hb.y * ib.y + hb.z * ib.z + hb.w * ib.w;
        #pragma unroll
        for (int off = 1; off < 16; off <<= 1) {
            dot0 += __shfl_xor(dot0, off);
            dot1 += __shfl_xor(dot1, off);
        }
        if ((threadIdx.x & 15) == 0) {
            float g0 = gb[0];
            float2 o2 = make_float2(dot0 + b_user[s0] + b_item[d0] + g0,
                                    dot1 + b_user[s1] + b_item[d1] + g0);
            *reinterpret_cast<float2*>(out + e0) = o2;
        }
    } else {
        int rb = b - NB_SCOR;
        int stride = NB_REG * 256;
        float local = 0.0f;
        const int TOT = (UN + IN_) * 16;
        for (int tid = rb * 256 + threadIdx.x; tid < TOT; tid += stride) {
            int r = tid >> 4;
            int c = (tid & 15) << 2;
            if (r < UN) {
                float4 p = *reinterpret_cast<const float4*>(pq_user + ((long)r << 6) + c);
                float4 y = *reinterpret_cast<const float4*>(yw_user + ((long)r << 6) + c);
                float sp = p.x * p.x + p.y * p.y + p.z * p.z + p.w * p.w;
                float sy = y.x * y.x + y.y * y.y + y.z * y.z + y.w * y.w;
                #pragma unroll
                for (int off = 1; off < 16; off <<= 1) {
                    sp += __shfl_xor(sp, off);
                    sy += __shfl_xor(sy, off);
                }
                if ((tid & 15) == 0) {
                    float Iu  = degfac_i(cur_r[r]);
                    float Tu  = degfac_i(cur_t[r]);
                    float Tvp = degfac_i(dto[r]);
                    float bb  = b_user[r];
                    local += ((LAMDA * Iu) * (bb * bb)
                            + (LAMDA * Iu + LAMDA_T * Tu) * sp
                            + (LAMDA_T * Tvp) * sy) * (1.0f / UN);
                }
            } else {
                int it = r - UN;
                float4 p = *reinterpret_cast<const float4*>(pq_item + ((long)it << 6) + c);
                float4 y = *reinterpret_cast<const float4*>(yw_item + ((long)it << 6) + c);
                float sp = p.x * p.x + p.y * p.y + p.z * p.z + p.w * p.w;
                float sy = y.x * y.x + y.y * y.y + y.z * y.z + y.w * y.w;
                #pragma unroll
                for (int off = 1; off < 16; off <<= 1) {
                    sp += __shfl_xor(sp, off);
                    sy += __shfl_xor(sy, off);
                }
                if ((tid & 15) == 0) {
                    float Uj = degfac_i(dri[it]);
                    float bb = b_item[it];
                    local += (LAMDA * Uj) * (bb * bb + sp + sy) * (1.0f / IN_);
                }
            }
        }
        #pragma unroll
        for (int off = 32; off > 0; off >>= 1) local += __shfl_xor(local, off);
        __shared__ float red[4];
        if ((threadIdx.x & 63) == 0) red[threadIdx.x >> 6] = local;
        __syncthreads();
        if (threadIdx.x == 0) unsafeAtomicAdd(acc + 1, (double)(red[0] + red[1] + red[2] + red[3]));
    }
}

__global__ void k_final(const double* __restrict__ acc, float* __restrict__ out) {
    if (threadIdx.x == 0 && blockIdx.x == 0) {
        out[2 * EPRED]     = (float)acc[1];
        out[2 * EPRED + 1] = (float)(LAMDA_T * acc[0] / (double)ETRUST);
    }
}

extern "C" void kernel_launch(void* const* d_in, const int* in_sizes, int n_in,
                              void* d_out, int out_size, void* d_ws, size_t ws_size,
                              hipStream_t stream) {
    const float* pq_user = (const float*)d_in[0];
    const float* pq_item = (const float*)d_in[1];
    const float* yw_user = (const float*)d_in[2];
    const float* yw_item = (const float*)d_in[3];
    const float* b_user  = (const float*)d_in[4];
    const float* b_item  = (const float*)d_in[5];
    const float* gb      = (const float*)d_in[6];
    const int* rate_src  = (const int*)d_in[7];
    const int* rate_dst  = (const int*)d_in[8];
    const int* trust_src = (const int*)d_in[9];
    const int* trust_dst = (const int*)d_in[10];
    const int* pos_src   = (const int*)d_in[11];
    const int* pos_dst   = (const int*)d_in[12];
    const int* neg_src   = (const int*)d_in[13];
    const int* neg_dst   = (const int*)d_in[14];

    float* ws   = (float*)d_ws;
    int*   wsi  = (int*)d_ws;
    float* h     = ws;
    int*   csr_r = wsi + OFF_CSR_R;
    int*   csr_t = wsi + OFF_CSR_T;
    int*   cur_r = wsi + OFF_CUR_R;
    int*   cur_t = wsi + OFF_CUR_T;
    int*   dri   = wsi + OFF_DRI;
    int*   dto   = wsi + OFF_DTO;
    double* acc  = (double*)((char*)d_ws + OFF_ACC_B);
    float* out   = (float*)d_out;

    // 1. zero cursors/hists/acc (contiguous)
    k_zero<<<(ZERO_N + 255) / 256, 256, 0, stream>>>(wsi + OFF_CUR_R, ZERO_N);
    // 2. A: batched bucket fills + link loss
    k_fillA<<<NB_FILLR + NB_FILLT + NB_LINK, 256, 0, stream>>>(
        rate_src, rate_dst, trust_src, trust_dst, yw_user, pq_user,
        cur_r, csr_r, cur_t, csr_t, acc);
    // 3. B: batched degree histograms + gather h (8 loads in flight per wave)
    k_gathB<<<NB_HISTR + NB_HISTT + NB_GATH, 256, 0, stream>>>(
        rate_dst, trust_src, pq_user, yw_item, yw_user,
        cur_r, csr_r, cur_t, csr_t, dri, dto, h);
    // 4. C: scores (2 edges/group) + reg loss
    k_scorC<<<NB_SCOR + NB_REG, 256, 0, stream>>>(
        h, pq_item, pq_user, yw_user, yw_item, b_user, b_item, gb,
        pos_src, pos_dst, neg_src, neg_dst,
        cur_r, cur_t, dto, dri, acc, out);
    // 5. finalize scalars
    k_final<<<1, 64, 0, stream>>>(acc, out);
}